// Round 6
// baseline (326.791 us; speedup 1.0000x reference)
//
#include <hip/hip_runtime.h>
#include <math.h>

// Problem constants
#define BB    512
#define NNODE 64
#define LLEN  64
#define DD    100
#define NNODES 50000
#define NM1   49999     // n_nodes - 1
#define KP    128       // padded K for emb/h (4 k-steps of 32)
#define KAV   224       // padded K for av section (7 k-steps)
#define KTOT  352       // KAV + KP
#define NCB   391       // ceil(49999/128) logits col-blocks
#define SHIFT 20.0f

typedef __attribute__((ext_vector_type(8))) short short8;
typedef __attribute__((ext_vector_type(4))) short short4_t;
typedef __attribute__((ext_vector_type(4))) float f32x4;
typedef unsigned short ushort_t;

__device__ __forceinline__ float sigm(float x) { return 1.0f / (1.0f + __expf(-x)); }
__device__ __forceinline__ float mytanh(float x) {
  x = fminf(15.0f, fmaxf(-15.0f, x));
  float e = __expf(-2.0f * x);
  return (1.0f - e) / (1.0f + e);
}
__device__ __forceinline__ float f4c(const float4& v, int k) { return ((const float*)&v)[k]; }
__device__ __forceinline__ ushort_t f2bf(float f) {  // RNE float->bf16
  union { float f; unsigned u; } v; v.f = f;
  unsigned r = v.u + 0x7FFF + ((v.u >> 16) & 1);
  return (ushort_t)(r >> 16);
}
__device__ __forceinline__ float bf2f(ushort_t s) {
  union { unsigned u; float f; } v; v.u = ((unsigned)s) << 16;
  return v.f;
}
__device__ __forceinline__ short8 cvt8(const float* __restrict__ p) {
  float4 v0 = *(const float4*)p, v1 = *(const float4*)(p + 4);
  short8 r;
  r[0] = (short)f2bf(v0.x); r[1] = (short)f2bf(v0.y);
  r[2] = (short)f2bf(v0.z); r[3] = (short)f2bf(v0.w);
  r[4] = (short)f2bf(v1.x); r[5] = (short)f2bf(v1.y);
  r[6] = (short)f2bf(v1.z); r[7] = (short)f2bf(v1.w);
  return r;
}

// ---------------------------------------------------------------------------
// C0: merged conversions. bid<6250: emb fp32 -> eb2 bf16 [50000][128].
// bid>=6250: the three k_cvt_w paths (y = (bid-6250)/287).
// Also zeroes out[0] (loss accumulator for k_lse_loss's atomicAdd).
// ---------------------------------------------------------------------------
__global__ __launch_bounds__(256) void k_cvt_all(
    const float* __restrict__ emb,
    const float* __restrict__ Wi, const float* __restrict__ Wo,
    const float* __restrict__ gk, const float* __restrict__ ck,
    ushort_t* __restrict__ eb2, ushort_t* __restrict__ WioT,
    ushort_t* __restrict__ gkT, ushort_t* __restrict__ ckT,
    float* __restrict__ out)
{
  const int bid = blockIdx.x, t = threadIdx.x;
  if (bid == 0 && t == 0) out[0] = 0.0f;
  if (bid < 6250) {
    const int tid = bid * 256 + t;
    const int r = tid >> 5, c4 = (tid & 31) * 4;
    if (r >= NNODES) return;
    short4_t o = {0, 0, 0, 0};
    if (c4 < DD) {
      float4 v = *(const float4*)(emb + (size_t)r * DD + c4);
      o.x = (short)f2bf(f4c(v, 0)); o.y = (short)f2bf(f4c(v, 1));
      o.z = (short)f2bf(f4c(v, 2)); o.w = (short)f2bf(f4c(v, 3));
    }
    *(short4_t*)(eb2 + (size_t)r * KP + c4) = o;
    return;
  }
  const int rem = bid - 6250;        // 0..860
  const int y = rem / 287;
  const int idx = (rem - y * 287) * 256 + t;
  if (y == 0) {
    if (idx >= 208 * 128) return;
    int n = idx >> 7, k = idx & 127;
    float v = 0.0f;
    if (k < DD) {
      if (n < 100) v = Wi[k * DD + n];
      else if (n < 200) v = Wo[k * DD + (n - 100)];
    }
    WioT[idx] = f2bf(v);
  } else if (y == 1) {
    if (idx >= 208 * KTOT) return;
    int n = idx / KTOT, k = idx - n * KTOT;
    float v = 0.0f;
    if (n < 200) {
      if (k < KAV) { if (k < 200) v = gk[k * 200 + n]; }
      else { int kk = k - KAV; if (kk < 100) v = gk[(200 + kk) * 200 + n]; }
    }
    gkT[idx] = f2bf(v);
  } else {
    if (idx >= 112 * KTOT) return;
    int n = idx / KTOT, k = idx - n * KTOT;
    float v = 0.0f;
    if (n < 100) {
      if (k < KAV) { if (k < 200) v = ck[k * DD + n]; }
      else { int kk = k - KAV; if (kk < 100) v = ck[(200 + kk) * DD + n]; }
    }
    ckT[idx] = f2bf(v);
  }
}

// ---------------------------------------------------------------------------
// K1: FUSED fio+av+GRU+attn. One block per batch b, 512 threads (8 waves).
// Wave w: rw = w&3 (16-row stripe), ch = w>>2 (column half / matrix half).
// All intermediates (fi/fo, av, r*h, u, fin) live in LDS — avb (29 MB) and
// fin2 (26 MB) global round trips are eliminated, along with 2 launches.
// Math is identical to the separate k_fio_av / k_gru_mfma / k_attn kernels.
//
// LDS pool (104.4 KB, region reuse; 1 block/CU, 2 waves/SIMD):
//   R1 [   0..32255]: s_f[2][112][72]us (A,B) -> s_rh[64][136]us (C,D)
//                      -> s_m[64][104]f (E2,E3)
//   R2 [32256..61951]: s_av[64][232]us (B..afa load) -> s_fin[64][104]f (D..E)
//   R3 [61952..79359]: s_h[64][136]us (staged; read C,D)
//   R4 [79360..105983]: s_u[64][104]f (C,D)
//   SM [105984..]:     s_last[104]f, s_coef[64]f, s_idx[64]i, s_lastid
// ---------------------------------------------------------------------------
__global__ __launch_bounds__(512) void k_fused(
    const ushort_t* __restrict__ eb2, const int* __restrict__ item,
    const ushort_t* __restrict__ WioT,
    const float* __restrict__ bi, const float* __restrict__ bo,
    const float* __restrict__ adj_in, const float* __restrict__ adj_out,
    const ushort_t* __restrict__ gkT, const float* __restrict__ gb,
    const ushort_t* __restrict__ ckT, const float* __restrict__ cbs,
    const int* __restrict__ alias_, const float* __restrict__ mask,
    const float* __restrict__ w1, const float* __restrict__ w2,
    const float* __restrict__ nv, const float* __restrict__ nb,
    ushort_t* __restrict__ mab)
{
  __shared__ __align__(16) char pool[106928];
  ushort_t (*s_f)[112][72] = (ushort_t (*)[112][72])(pool);
  ushort_t (*s_rh)[136]    = (ushort_t (*)[136])(pool);
  float    (*s_m)[104]     = (float (*)[104])(pool);
  ushort_t (*s_av)[232]    = (ushort_t (*)[232])(pool + 32256);
  float    (*s_fin)[104]   = (float (*)[104])(pool + 32256);
  ushort_t (*s_h)[136]     = (ushort_t (*)[136])(pool + 61952);
  float    (*s_u)[104]     = (float (*)[104])(pool + 79360);
  float* s_last   = (float*)(pool + 105984);
  float* s_coef   = (float*)(pool + 106400);
  int*   s_idx    = (int*)(pool + 106656);
  int*   s_lastid = (int*)(pool + 106912);

  const int t = threadIdx.x;
  const int w8 = t >> 6, lane = t & 63;
  const int rw = w8 & 3, ch = w8 >> 2;
  const int n16 = lane & 15, quad = lane >> 4;
  const int b = blockIdx.x;

  // ---- A0: stage h (64 rows x 128 bf16) + zero pads ----
  {
    const int row = t >> 3, seg = t & 7;   // 8 segs x 16 ushort
    const ushort_t* hsrc = eb2 + (size_t)item[b * 64 + row] * KP + seg * 16;
    *(short8*)&s_h[row][seg * 16]     = *(const short8*)(hsrc);
    *(short8*)&s_h[row][seg * 16 + 8] = *(const short8*)(hsrc + 8);
  }
  if (t >= 64 && t < 128) {            // zero s_av cols 200..223 (afa ks=6 pad)
    const int r2 = t - 64;
#pragma unroll
    for (int c = 200; c < 224; ++c) s_av[r2][c] = 0;
  }
  for (int idx = t; idx < 2 * 12 * 64; idx += 512) {   // s_f pad rows 100..111
    int which = idx / 768, rem = idx - which * 768;
    s_f[which][100 + rem / 64][rem & 63] = 0;
  }
  __syncthreads();   // B1

  // af = h fragment for stripe rw (also the GRU's afh)
  short8 af[4];
#pragma unroll
  for (int ks = 0; ks < 4; ++ks)
    af[ks] = *(const short8*)&s_h[rw * 16 + n16][quad * 8 + ks * 32];

  // ---- A: fio = h @ [Wi|Wo] + bias -> s_f (transposed [col][node]) ----
  {
    const int node0 = rw * 16 + quad * 4;
    const int s0 = ch ? 7 : 0, s1 = ch ? 13 : 7;
    for (int sub = s0; sub < s1; ++sub) {
      const ushort_t* brow = WioT + (size_t)(sub * 16 + n16) * KP + quad * 8;
      f32x4 acc = {0.0f, 0.0f, 0.0f, 0.0f};
#pragma unroll
      for (int ks = 0; ks < 4; ++ks)
        acc = __builtin_amdgcn_mfma_f32_16x16x32_bf16(af[ks], *(const short8*)(brow + ks * 32), acc, 0, 0, 0);
      const int col = sub * 16 + n16;
      if (col < 200) {
        const float bias = (col < 100) ? bi[col] : bo[col - 100];
        short4_t st;
#pragma unroll
        for (int r = 0; r < 4; ++r) ((ushort_t*)&st)[r] = f2bf(acc[r] + bias);
        const int which = (col < 100) ? 0 : 1;
        const int c = (col < 100) ? col : col - 100;
        *(short4_t*)&s_f[which][c][node0] = st;
      }
    }
  }
  __syncthreads();   // B2

  // ---- B: av. ch=0: adj_in@fi -> cols 0..99; ch=1: adj_out@fo -> 100..199 ----
  {
    const float* aX = (ch ? adj_out : adj_in)
                      + ((size_t)b * 64 + rw * 16 + n16) * 64 + quad * 8;
    short8 afX[2];
    afX[0] = cvt8(aX); afX[1] = cvt8(aX + 32);
    for (int sub = 0; sub < 7; ++sub) {
      const int col = sub * 16 + n16;
      const ushort_t* bX = &s_f[ch][col][quad * 8];
      f32x4 acc = {0.0f, 0.0f, 0.0f, 0.0f};
#pragma unroll
      for (int ks = 0; ks < 2; ++ks)
        acc = __builtin_amdgcn_mfma_f32_16x16x32_bf16(afX[ks], *(const short8*)(bX + ks * 32), acc, 0, 0, 0);
      if (col < 100) {
#pragma unroll
        for (int r = 0; r < 4; ++r)
          s_av[rw * 16 + quad * 4 + r][ch * 100 + col] = f2bf(acc[r]);
      }
    }
  }
  __syncthreads();   // B3

  // Region1 transitions s_f -> s_rh: zero pad cols 100..127 (afr ks=3 pad)
  if (t < 64) {
#pragma unroll
    for (int c = 100; c < 128; ++c) s_rh[t][c] = 0;
  }
  // afa = av fragment for stripe rw
  short8 afa[7];
#pragma unroll
  for (int ks = 0; ks < 7; ++ks)
    afa[ks] = *(const short8*)&s_av[rw * 16 + n16][quad * 8 + ks * 32];

  // ---- C: gates = sigm([av|h] @ gkT + gb); r*h -> s_rh, u -> s_u ----
  {
    const int s0 = ch ? 7 : 0, s1 = ch ? 13 : 7;
    for (int sub = s0; sub < s1; ++sub) {
      const ushort_t* brow = gkT + (size_t)(sub * 16 + n16) * KTOT + quad * 8;
      f32x4 acc = {0.0f, 0.0f, 0.0f, 0.0f};
#pragma unroll
      for (int ks = 0; ks < 7; ++ks)
        acc = __builtin_amdgcn_mfma_f32_16x16x32_bf16(afa[ks], *(const short8*)(brow + ks * 32), acc, 0, 0, 0);
#pragma unroll
      for (int ks = 0; ks < 4; ++ks)
        acc = __builtin_amdgcn_mfma_f32_16x16x32_bf16(af[ks], *(const short8*)(brow + KAV + ks * 32), acc, 0, 0, 0);
      const int col = sub * 16 + n16;
      if (col < 200) {
        const float bias = gb[col];
#pragma unroll
        for (int r = 0; r < 4; ++r) {
          const int row = rw * 16 + quad * 4 + r;
          const float g = sigm(acc[r] + bias);
          if (col < 100) s_rh[row][col] = f2bf(g * bf2f(s_h[row][col]));
          else           s_u[row][col - 100] = g;
        }
      }
    }
  }
  __syncthreads();   // B4

  // afr = (r*h) fragment
  short8 afr[4];
#pragma unroll
  for (int ks = 0; ks < 4; ++ks)
    afr[ks] = *(const short8*)&s_rh[rw * 16 + n16][quad * 8 + ks * 32];

  // ---- D: c = tanh([av|r*h] @ ckT + cb); fin = u*h + (1-u)*c -> s_fin ----
  {
    const int s0 = ch ? 4 : 0, s1 = ch ? 7 : 4;
    for (int sub = s0; sub < s1; ++sub) {
      const ushort_t* brow = ckT + (size_t)(sub * 16 + n16) * KTOT + quad * 8;
      f32x4 acc = {0.0f, 0.0f, 0.0f, 0.0f};
#pragma unroll
      for (int ks = 0; ks < 7; ++ks)
        acc = __builtin_amdgcn_mfma_f32_16x16x32_bf16(afa[ks], *(const short8*)(brow + ks * 32), acc, 0, 0, 0);
#pragma unroll
      for (int ks = 0; ks < 4; ++ks)
        acc = __builtin_amdgcn_mfma_f32_16x16x32_bf16(afr[ks], *(const short8*)(brow + KAV + ks * 32), acc, 0, 0, 0);
      const int col = sub * 16 + n16;
      if (col < 100) {
        const float bias = cbs[col];
#pragma unroll
        for (int r = 0; r < 4; ++r) {
          const int row = rw * 16 + quad * 4 + r;
          const float c_ = mytanh(acc[r] + bias);
          const float u = s_u[row][col];
          const float hv = bf2f(s_h[row][col]);
          s_fin[row][col] = u * hv + (1.0f - u) * c_;
        }
      }
    }
  }
  __syncthreads();   // B5

  // ---- E0: lastid (wave0 shuffle reduce) + alias index table ----
  if (t < 64) {
    float v = mask[b * LLEN + t];
    v += __shfl_xor(v, 1, 64);  v += __shfl_xor(v, 2, 64);
    v += __shfl_xor(v, 4, 64);  v += __shfl_xor(v, 8, 64);
    v += __shfl_xor(v, 16, 64); v += __shfl_xor(v, 32, 64);
    if (t == 0) {
      int rm = (int)(v + 0.5f);
      *s_lastid = alias_[b * LLEN + rm - 1];
    }
  } else if (t < 128) {
    s_idx[t - 64] = alias_[b * LLEN + (t - 64)];
  }
  __syncthreads();   // B6

  // ---- E1: s_last[e] = fin[lastid] @ w1 ----
  if (t < DD) {
    const float* lh = s_fin[*s_lastid];
    float acc = 0.0f;
#pragma unroll 4
    for (int k = 0; k < DD; ++k) acc += lh[k] * w1[k * DD + t];
    s_last[t] = acc;
  }
  __syncthreads();   // B7

  // ---- E2: s_m = sigm(seq_h @ w2 + last + nb); 16 ty-groups x 4 rows ----
  {
    const int tx = t & 31, ty = t >> 5, cb4 = tx * 4;
    if (cb4 < DD) {
      float acc[4][4] = {};
      const float* frs[4] = { s_fin[s_idx[ty * 4 + 0]], s_fin[s_idx[ty * 4 + 1]],
                              s_fin[s_idx[ty * 4 + 2]], s_fin[s_idx[ty * 4 + 3]] };
      for (int k4 = 0; k4 < 25; ++k4) {
        float4 bv[4];
#pragma unroll
        for (int kk = 0; kk < 4; ++kk)
          bv[kk] = *(const float4*)(w2 + (size_t)(k4 * 4 + kk) * DD + cb4);
#pragma unroll
        for (int i = 0; i < 4; ++i) {
          float4 a = *(const float4*)(frs[i] + k4 * 4);
#pragma unroll
          for (int kk = 0; kk < 4; ++kk) {
            float av_ = f4c(a, kk);
#pragma unroll
            for (int j = 0; j < 4; ++j) acc[i][j] += av_ * f4c(bv[kk], j);
          }
        }
      }
#pragma unroll
      for (int i = 0; i < 4; ++i) {
        const int l = ty * 4 + i;
#pragma unroll
        for (int j = 0; j < 4; ++j) {
          const int e = cb4 + j;
          s_m[l][e] = sigm(acc[i][j] + s_last[e] + nb[e]);
        }
      }
    }
  }
  __syncthreads();   // B8

  // ---- E3: coef[l] = (m[l] . nv) * mask[l] ----
  if (t < LLEN) {
    float acc = 0.0f;
#pragma unroll 4
    for (int e = 0; e < DD; ++e) acc += s_m[t][e] * nv[e];
    s_coef[t] = acc * mask[b * LLEN + t];
  }
  __syncthreads();   // B9

  // ---- E4: ma[d] = sum_l coef[l] * seq_h[l][d] -> mab ----
  if (t < DD) {
    float acc = 0.0f;
#pragma unroll 4
    for (int l = 0; l < LLEN; ++l) acc += s_coef[l] * s_fin[s_idx[l]][t];
    mab[(size_t)b * KP + t] = f2bf(acc);
  } else if (t < KP) {
    mab[(size_t)b * KP + t] = 0;
  }
}

// ---------------------------------------------------------------------------
// K4: logits = mab @ eb2[1:]^T via MFMA — round-5 variant (best measured,
// 64.3 us; parked: 102 MB mandatory output at the ~1.6 TB/s streaming-write
// plateau observed across 4 structural variants).
// ---------------------------------------------------------------------------
__global__ __launch_bounds__(256) void k_logits_mfma(
    const ushort_t* __restrict__ eb2, const ushort_t* __restrict__ mab,
    float* __restrict__ out, float* __restrict__ sump)
{
  __shared__ float s_o[16][512];   // block C tile: 16 rows x 512 cols
  const int t = threadIdx.x;
  const int wave = t >> 6, lane = t & 63;
  const int n16 = lane & 15, quad = lane >> 4;
  const int bid = blockIdx.x;
  const int xcd = bid & 7;
  const int j = bid >> 3;                    // 0..415
  const int grpl = j >> 5;                   // local col-group 0..12
  const int lgmax = (xcd < 2) ? 13 : 12;     // 98 = 2*13 + 6*12
  if (grpl >= lgmax) return;
  const int stripe = j & 31;                 // fast-varying: 32 row-stripes
  const int cg = ((xcd < 2) ? xcd * 13 : 26 + (xcd - 2) * 12) + grpl; // 0..97
  const int m0 = stripe * 16;
  const int cblk = cg * 4 + wave;            // this wave's 128-col block

  short8 afr[4];
  const ushort_t* abase = mab + (size_t)(m0 + n16) * KP + quad * 8;
#pragma unroll
  for (int ks = 0; ks < 4; ++ks) afr[ks] = *(const short8*)(abase + ks * 32);

  float s[4] = {0.0f, 0.0f, 0.0f, 0.0f};
  if (cblk < NCB) {
#pragma unroll
    for (int sub = 0; sub < 8; ++sub) {
      const int c = cblk * 128 + sub * 16 + n16;
      const ushort_t* bbase = eb2 + (size_t)((c < NM1) ? (c + 1) : 0) * KP + quad * 8;
      f32x4 acc = {0.0f, 0.0f, 0.0f, 0.0f};
#pragma unroll
      for (int ks = 0; ks < 4; ++ks) {
        short8 bfr = *(const short8*)(bbase + ks * 32);
        acc = __builtin_amdgcn_mfma_f32_16x16x32_bf16(afr[ks], bfr, acc, 0, 0, 0);
      }
#pragma unroll
      for (int r = 0; r < 4; ++r) {
        s_o[quad * 4 + r][wave * 128 + sub * 16 + n16] = acc[r];
        if (c < NM1) s[r] += __expf(acc[r] - SHIFT);
      }
    }
  }
  __syncthreads();

  // store: 8 iters x (2 rows x 2048 B contiguous runs)
  float* lgp = out + 1;
  const int half = t >> 7, tc = t & 127;
#pragma unroll
  for (int it = 0; it < 8; ++it) {
    const int row = it * 2 + half;
    const size_t gr = m0 + row;
    f32x4 v = *(const f32x4*)&s_o[row][tc * 4];
    const int c0 = cg * 512 + tc * 4;
    if (c0 + 3 < NM1) {
      __builtin_nontemporal_store(v, (f32x4*)(lgp + gr * NM1 + c0));
    } else {
#pragma unroll
      for (int e = 0; e < 4; ++e)
        if (c0 + e < NM1)
          __builtin_nontemporal_store(v[e], lgp + gr * NM1 + c0 + e);
    }
  }

  if (cblk < NCB) {
    const int row0 = m0 + quad * 4;
#pragma unroll
    for (int r = 0; r < 4; ++r) {
      float x = s[r];
      x += __shfl_xor(x, 1, 64);
      x += __shfl_xor(x, 2, 64);
      x += __shfl_xor(x, 4, 64);
      x += __shfl_xor(x, 8, 64);
      if (n16 == 0) sump[(size_t)(row0 + r) * NCB + cblk] = x;
    }
  }
}

// ---------------------------------------------------------------------------
// K5: fused LSE + loss. Per row r: rt = logits[r][label] - (log(sum)+SHIFT);
// atomicAdd(-rt/BB) into out[0] (zeroed by k_cvt_all at iteration start).
// ---------------------------------------------------------------------------
__global__ __launch_bounds__(64) void k_lse_loss(
    const float* __restrict__ sump, float* __restrict__ out,
    const int* __restrict__ tar)
{
  const int r = blockIdx.x, t = threadIdx.x;
  float s = 0.0f;
  for (int i = t; i < NCB; i += 64) s += sump[(size_t)r * NCB + i];
  for (int m = 1; m < 64; m <<= 1) s += __shfl_xor(s, m, 64);
  if (t == 0) {
    int label = tar[r] - 1;
    const float* lg = out + 1;
    float rt = lg[(size_t)r * NM1 + label] - (logf(s) + SHIFT);
    atomicAdd(out, -rt / (float)BB);
  }
}

// ---------------------------------------------------------------------------
extern "C" void kernel_launch(void* const* d_in, const int* in_sizes, int n_in,
                              void* d_out, int out_size, void* d_ws, size_t ws_size,
                              hipStream_t stream)
{
  (void)in_sizes; (void)n_in; (void)out_size; (void)ws_size;
  const float* adj_in  = (const float*)d_in[0];
  const float* adj_out = (const float*)d_in[1];
  const int*   item    = (const int*)d_in[2];
  const int*   alias_  = (const int*)d_in[3];
  const float* mask    = (const float*)d_in[4];
  const int*   tar     = (const int*)d_in[5];
  const float* emb     = (const float*)d_in[6];
  const float* W_in    = (const float*)d_in[7];
  const float* b_in    = (const float*)d_in[8];
  const float* W_out   = (const float*)d_in[9];
  const float* b_out   = (const float*)d_in[10];
  const float* gk      = (const float*)d_in[11];
  const float* gb      = (const float*)d_in[12];
  const float* ck      = (const float*)d_in[13];
  const float* cbs     = (const float*)d_in[14];
  const float* w1      = (const float*)d_in[15];
  const float* w2      = (const float*)d_in[16];
  const float* nv      = (const float*)d_in[17];
  const float* nb      = (const float*)d_in[18];
  float* out = (float*)d_out;

  // Workspace layout, ushort units (offsets kept from prior rounds).
  ushort_t* usw = (ushort_t*)d_ws;
  ushort_t* eb2  = usw;                    // 50000*128     = 6,400,000
  ushort_t* WioT = usw + 13740032;         // 208*128       = 26,624
  ushort_t* gkT  = usw + 13766656;         // 208*352       = 73,216
  ushort_t* ckT  = usw + 13839872;         // 112*352       = 39,424
  ushort_t* mab  = usw + 13879296;         // 512*128       = 65,536
  float* fpool   = (float*)(usw + 13944832);
  float* sump    = fpool + 3276800;        // 512*391       = 200,192

  k_cvt_all <<<dim3(7111), 256, 0, stream>>>(emb, W_in, W_out, gk, ck,
                                             eb2, WioT, gkT, ckT, out);
  k_fused   <<<dim3(512), 512, 0, stream>>>(eb2, item, WioT, b_in, b_out,
                                            adj_in, adj_out, gkT, gb, ckT, cbs,
                                            alias_, mask, w1, w2, nv, nb, mab);
  k_logits_mfma<<<dim3(3328), 256, 0, stream>>>(eb2, mab, out, sump);
  k_lse_loss<<<dim3(512), 64, 0, stream>>>(sump, out, tar);
}

// Round 7
// 312.429 us; speedup vs baseline: 1.0460x; 1.0460x over previous
//
#include <hip/hip_runtime.h>
#include <math.h>

// Problem constants
#define BB    512
#define NNODE 64
#define LLEN  64
#define DD    100
#define NNODES 50000
#define NM1   49999     // n_nodes - 1
#define KP    128       // padded K for emb/h (4 k-steps of 32)
#define KAV   224       // padded K for av section (7 k-steps)
#define KTOT  352       // KAV + KP
#define NCB   391       // ceil(49999/128) logits col-blocks
#define SHIFT 20.0f

typedef __attribute__((ext_vector_type(8))) short short8;
typedef __attribute__((ext_vector_type(4))) short short4_t;
typedef __attribute__((ext_vector_type(4))) float f32x4;
typedef unsigned short ushort_t;

__device__ __forceinline__ float sigm(float x) { return 1.0f / (1.0f + __expf(-x)); }
__device__ __forceinline__ float mytanh(float x) {
  x = fminf(15.0f, fmaxf(-15.0f, x));
  float e = __expf(-2.0f * x);
  return (1.0f - e) / (1.0f + e);
}
__device__ __forceinline__ float f4c(const float4& v, int k) { return ((const float*)&v)[k]; }
__device__ __forceinline__ ushort_t f2bf(float f) {  // RNE float->bf16
  union { float f; unsigned u; } v; v.f = f;
  unsigned r = v.u + 0x7FFF + ((v.u >> 16) & 1);
  return (ushort_t)(r >> 16);
}
__device__ __forceinline__ float bf2f(ushort_t s) {
  union { unsigned u; float f; } v; v.u = ((unsigned)s) << 16;
  return v.f;
}
__device__ __forceinline__ short8 cvt8(const float* __restrict__ p) {
  float4 v0 = *(const float4*)p, v1 = *(const float4*)(p + 4);
  short8 r;
  r[0] = (short)f2bf(v0.x); r[1] = (short)f2bf(v0.y);
  r[2] = (short)f2bf(v0.z); r[3] = (short)f2bf(v0.w);
  r[4] = (short)f2bf(v1.x); r[5] = (short)f2bf(v1.y);
  r[6] = (short)f2bf(v1.z); r[7] = (short)f2bf(v1.w);
  return r;
}

// ---------------------------------------------------------------------------
// C0: merged conversions + sumrow zeroing.
//   bid <  782 : emb fp32 -> eb2 bf16 [50000][128] (32 cols/thread)
//   782..1642  : the three k_cvt_w paths (y = (bid-782)/287)
//   bid == 1643: zero sumrow[512] (per-row exp-sum accumulator)
// ---------------------------------------------------------------------------
__global__ __launch_bounds__(256) void k_cvt_all(
    const float* __restrict__ emb,
    const float* __restrict__ Wi, const float* __restrict__ Wo,
    const float* __restrict__ gk, const float* __restrict__ ck,
    ushort_t* __restrict__ eb2, ushort_t* __restrict__ WioT,
    ushort_t* __restrict__ gkT, ushort_t* __restrict__ ckT,
    float* __restrict__ sumrow)
{
  const int bid = blockIdx.x, t = threadIdx.x;
  if (bid < 782) {
    const int tid = bid * 256 + t;
    const int r = tid >> 2;
    if (r >= NNODES) return;
    const int c0 = (tid & 3) * 32;
#pragma unroll
    for (int c4 = c0; c4 < c0 + 32; c4 += 4) {
      short4_t o = {0, 0, 0, 0};
      if (c4 < DD) {
        float4 v = *(const float4*)(emb + (size_t)r * DD + c4);
        o.x = (short)f2bf(f4c(v, 0)); o.y = (short)f2bf(f4c(v, 1));
        o.z = (short)f2bf(f4c(v, 2)); o.w = (short)f2bf(f4c(v, 3));
      }
      *(short4_t*)(eb2 + (size_t)r * KP + c4) = o;
    }
    return;
  }
  if (bid == 1643) {
    sumrow[t] = 0.0f;
    sumrow[t + 256] = 0.0f;
    return;
  }
  const int rem = bid - 782;         // 0..860
  const int y = rem / 287;
  const int idx = (rem - y * 287) * 256 + t;
  if (y == 0) {
    if (idx >= 208 * 128) return;
    int n = idx >> 7, k = idx & 127;
    float v = 0.0f;
    if (k < DD) {
      if (n < 100) v = Wi[k * DD + n];
      else if (n < 200) v = Wo[k * DD + (n - 100)];
    }
    WioT[idx] = f2bf(v);
  } else if (y == 1) {
    if (idx >= 208 * KTOT) return;
    int n = idx / KTOT, k = idx - n * KTOT;
    float v = 0.0f;
    if (n < 200) {
      if (k < KAV) { if (k < 200) v = gk[k * 200 + n]; }
      else { int kk = k - KAV; if (kk < 100) v = gk[(200 + kk) * 200 + n]; }
    }
    gkT[idx] = f2bf(v);
  } else {
    if (idx >= 112 * KTOT) return;
    int n = idx / KTOT, k = idx - n * KTOT;
    float v = 0.0f;
    if (n < 100) {
      if (k < KAV) { if (k < 200) v = ck[k * DD + n]; }
      else { int kk = k - KAV; if (kk < 100) v = ck[(200 + kk) * DD + n]; }
    }
    ckT[idx] = f2bf(v);
  }
}

// ---------------------------------------------------------------------------
// K1: FUSED fio+av+GRU+attn. One block per batch b, 512 threads (8 waves).
// Round-7: LDS pool cut 106.9 -> 80.3 KB (u-gate stored bf16, packed into
// the dead s_f region beside s_rh) => 2 blocks/CU, all 512 blocks resident
// simultaneously (R6 post-mortem: 1 block/CU + 2 rounds = 22% occupancy was
// the cost). Math otherwise identical to R6 (absmax 0.125, margin >= 0.25;
// bf16-u adds ~0.004 abs error to fin).
//
// LDS pool (80,320 B):
//   R1 [    0..32255]: s_f[2][112][72]us (A,B)
//                      -> s_rh[64][136]us @0 + s_ub[64][104]us @17408 (C,D)
//                      -> s_m[64][104]f @0 (E2,E3)
//   R2 [32256..61951]: s_av[64][232]us (B..afa reg load) -> s_fin[64][104]f
//   R3 [61952..79359]: s_h[64][136]us (A0..D)
//   SM [79360..]     : s_last[104]f, s_coef[64]f, s_idx[64]i, s_lastid
// ---------------------------------------------------------------------------
__global__ __launch_bounds__(512) void k_fused(
    const ushort_t* __restrict__ eb2, const int* __restrict__ item,
    const ushort_t* __restrict__ WioT,
    const float* __restrict__ bi, const float* __restrict__ bo,
    const float* __restrict__ adj_in, const float* __restrict__ adj_out,
    const ushort_t* __restrict__ gkT, const float* __restrict__ gb,
    const ushort_t* __restrict__ ckT, const float* __restrict__ cbs,
    const int* __restrict__ alias_, const float* __restrict__ mask,
    const float* __restrict__ w1, const float* __restrict__ w2,
    const float* __restrict__ nv, const float* __restrict__ nb,
    ushort_t* __restrict__ mab)
{
  __shared__ __align__(16) char pool[80320];
  ushort_t (*s_f)[112][72] = (ushort_t (*)[112][72])(pool);
  ushort_t (*s_rh)[136]    = (ushort_t (*)[136])(pool);
  ushort_t (*s_ub)[104]    = (ushort_t (*)[104])(pool + 17408);
  float    (*s_m)[104]     = (float (*)[104])(pool);
  ushort_t (*s_av)[232]    = (ushort_t (*)[232])(pool + 32256);
  float    (*s_fin)[104]   = (float (*)[104])(pool + 32256);
  ushort_t (*s_h)[136]     = (ushort_t (*)[136])(pool + 61952);
  float* s_last   = (float*)(pool + 79360);
  float* s_coef   = (float*)(pool + 79776);
  int*   s_idx    = (int*)(pool + 80032);
  int*   s_lastid = (int*)(pool + 80288);

  const int t = threadIdx.x;
  const int w8 = t >> 6, lane = t & 63;
  const int rw = w8 & 3, ch = w8 >> 2;
  const int n16 = lane & 15, quad = lane >> 4;
  const int b = blockIdx.x;

  // ---- A0: stage h (64 rows x 128 bf16) + zero pads ----
  {
    const int row = t >> 3, seg = t & 7;   // 8 segs x 16 ushort
    const ushort_t* hsrc = eb2 + (size_t)item[b * 64 + row] * KP + seg * 16;
    *(short8*)&s_h[row][seg * 16]     = *(const short8*)(hsrc);
    *(short8*)&s_h[row][seg * 16 + 8] = *(const short8*)(hsrc + 8);
  }
  if (t >= 64 && t < 128) {            // zero s_av cols 200..223 (afa ks=6 pad)
    const int r2 = t - 64;
#pragma unroll
    for (int c = 200; c < 224; ++c) s_av[r2][c] = 0;
  }
  for (int idx = t; idx < 2 * 12 * 64; idx += 512) {   // s_f pad rows 100..111
    int which = idx / 768, rem = idx - which * 768;
    s_f[which][100 + rem / 64][rem & 63] = 0;
  }
  __syncthreads();   // B1

  // af = h fragment for stripe rw (also the GRU's afh)
  short8 af[4];
#pragma unroll
  for (int ks = 0; ks < 4; ++ks)
    af[ks] = *(const short8*)&s_h[rw * 16 + n16][quad * 8 + ks * 32];

  // ---- A: fio = h @ [Wi|Wo] + bias -> s_f (transposed [col][node]) ----
  {
    const int node0 = rw * 16 + quad * 4;
    const int s0 = ch ? 7 : 0, s1 = ch ? 13 : 7;
    for (int sub = s0; sub < s1; ++sub) {
      const ushort_t* brow = WioT + (size_t)(sub * 16 + n16) * KP + quad * 8;
      f32x4 acc = {0.0f, 0.0f, 0.0f, 0.0f};
#pragma unroll
      for (int ks = 0; ks < 4; ++ks)
        acc = __builtin_amdgcn_mfma_f32_16x16x32_bf16(af[ks], *(const short8*)(brow + ks * 32), acc, 0, 0, 0);
      const int col = sub * 16 + n16;
      if (col < 200) {
        const float bias = (col < 100) ? bi[col] : bo[col - 100];
        short4_t st;
#pragma unroll
        for (int r = 0; r < 4; ++r) ((ushort_t*)&st)[r] = f2bf(acc[r] + bias);
        const int which = (col < 100) ? 0 : 1;
        const int c = (col < 100) ? col : col - 100;
        *(short4_t*)&s_f[which][c][node0] = st;
      }
    }
  }
  __syncthreads();   // B2

  // ---- B: av. ch=0: adj_in@fi -> cols 0..99; ch=1: adj_out@fo -> 100..199 ----
  {
    const float* aX = (ch ? adj_out : adj_in)
                      + ((size_t)b * 64 + rw * 16 + n16) * 64 + quad * 8;
    short8 afX[2];
    afX[0] = cvt8(aX); afX[1] = cvt8(aX + 32);
    for (int sub = 0; sub < 7; ++sub) {
      const int col = sub * 16 + n16;
      const ushort_t* bX = &s_f[ch][col][quad * 8];
      f32x4 acc = {0.0f, 0.0f, 0.0f, 0.0f};
#pragma unroll
      for (int ks = 0; ks < 2; ++ks)
        acc = __builtin_amdgcn_mfma_f32_16x16x32_bf16(afX[ks], *(const short8*)(bX + ks * 32), acc, 0, 0, 0);
      if (col < 100) {
#pragma unroll
        for (int r = 0; r < 4; ++r)
          s_av[rw * 16 + quad * 4 + r][ch * 100 + col] = f2bf(acc[r]);
      }
    }
  }
  __syncthreads();   // B3

  // Region1 transitions s_f -> s_rh/s_ub: zero pad cols 100..127 (afr pad)
  if (t < 64) {
#pragma unroll
    for (int c = 100; c < 128; ++c) s_rh[t][c] = 0;
  }
  // afa = av fragment for stripe rw
  short8 afa[7];
#pragma unroll
  for (int ks = 0; ks < 7; ++ks)
    afa[ks] = *(const short8*)&s_av[rw * 16 + n16][quad * 8 + ks * 32];

  // ---- C: gates = sigm([av|h] @ gkT + gb); r*h -> s_rh, u -> s_ub (bf16) ----
  {
    const int s0 = ch ? 7 : 0, s1 = ch ? 13 : 7;
    for (int sub = s0; sub < s1; ++sub) {
      const ushort_t* brow = gkT + (size_t)(sub * 16 + n16) * KTOT + quad * 8;
      f32x4 acc = {0.0f, 0.0f, 0.0f, 0.0f};
#pragma unroll
      for (int ks = 0; ks < 7; ++ks)
        acc = __builtin_amdgcn_mfma_f32_16x16x32_bf16(afa[ks], *(const short8*)(brow + ks * 32), acc, 0, 0, 0);
#pragma unroll
      for (int ks = 0; ks < 4; ++ks)
        acc = __builtin_amdgcn_mfma_f32_16x16x32_bf16(af[ks], *(const short8*)(brow + KAV + ks * 32), acc, 0, 0, 0);
      const int col = sub * 16 + n16;
      if (col < 200) {
        const float bias = gb[col];
#pragma unroll
        for (int r = 0; r < 4; ++r) {
          const int row = rw * 16 + quad * 4 + r;
          const float g = sigm(acc[r] + bias);
          if (col < 100) s_rh[row][col] = f2bf(g * bf2f(s_h[row][col]));
          else           s_ub[row][col - 100] = f2bf(g);
        }
      }
    }
  }
  __syncthreads();   // B4

  // afr = (r*h) fragment
  short8 afr[4];
#pragma unroll
  for (int ks = 0; ks < 4; ++ks)
    afr[ks] = *(const short8*)&s_rh[rw * 16 + n16][quad * 8 + ks * 32];

  // ---- D: c = tanh([av|r*h] @ ckT + cb); fin = u*h + (1-u)*c -> s_fin ----
  {
    const int s0 = ch ? 4 : 0, s1 = ch ? 7 : 4;
    for (int sub = s0; sub < s1; ++sub) {
      const ushort_t* brow = ckT + (size_t)(sub * 16 + n16) * KTOT + quad * 8;
      f32x4 acc = {0.0f, 0.0f, 0.0f, 0.0f};
#pragma unroll
      for (int ks = 0; ks < 7; ++ks)
        acc = __builtin_amdgcn_mfma_f32_16x16x32_bf16(afa[ks], *(const short8*)(brow + ks * 32), acc, 0, 0, 0);
#pragma unroll
      for (int ks = 0; ks < 4; ++ks)
        acc = __builtin_amdgcn_mfma_f32_16x16x32_bf16(afr[ks], *(const short8*)(brow + KAV + ks * 32), acc, 0, 0, 0);
      const int col = sub * 16 + n16;
      if (col < 100) {
        const float bias = cbs[col];
#pragma unroll
        for (int r = 0; r < 4; ++r) {
          const int row = rw * 16 + quad * 4 + r;
          const float c_ = mytanh(acc[r] + bias);
          const float u = bf2f(s_ub[row][col]);
          const float hv = bf2f(s_h[row][col]);
          s_fin[row][col] = u * hv + (1.0f - u) * c_;
        }
      }
    }
  }
  __syncthreads();   // B5

  // ---- E0: lastid (wave0 shuffle reduce) + alias index table ----
  if (t < 64) {
    float v = mask[b * LLEN + t];
    v += __shfl_xor(v, 1, 64);  v += __shfl_xor(v, 2, 64);
    v += __shfl_xor(v, 4, 64);  v += __shfl_xor(v, 8, 64);
    v += __shfl_xor(v, 16, 64); v += __shfl_xor(v, 32, 64);
    if (t == 0) {
      int rm = (int)(v + 0.5f);
      *s_lastid = alias_[b * LLEN + rm - 1];
    }
  } else if (t < 128) {
    s_idx[t - 64] = alias_[b * LLEN + (t - 64)];
  }
  __syncthreads();   // B6

  // ---- E1: s_last[e] = fin[lastid] @ w1 ----
  if (t < DD) {
    const float* lh = s_fin[*s_lastid];
    float acc = 0.0f;
#pragma unroll 4
    for (int k = 0; k < DD; ++k) acc += lh[k] * w1[k * DD + t];
    s_last[t] = acc;
  }
  __syncthreads();   // B7

  // ---- E2: s_m = sigm(seq_h @ w2 + last + nb); 16 ty-groups x 4 rows ----
  {
    const int tx = t & 31, ty = t >> 5, cb4 = tx * 4;
    if (cb4 < DD) {
      float acc[4][4] = {};
      const float* frs[4] = { s_fin[s_idx[ty * 4 + 0]], s_fin[s_idx[ty * 4 + 1]],
                              s_fin[s_idx[ty * 4 + 2]], s_fin[s_idx[ty * 4 + 3]] };
      for (int k4 = 0; k4 < 25; ++k4) {
        float4 bv[4];
#pragma unroll
        for (int kk = 0; kk < 4; ++kk)
          bv[kk] = *(const float4*)(w2 + (size_t)(k4 * 4 + kk) * DD + cb4);
#pragma unroll
        for (int i = 0; i < 4; ++i) {
          float4 a = *(const float4*)(frs[i] + k4 * 4);
#pragma unroll
          for (int kk = 0; kk < 4; ++kk) {
            float av_ = f4c(a, kk);
#pragma unroll
            for (int j = 0; j < 4; ++j) acc[i][j] += av_ * f4c(bv[kk], j);
          }
        }
      }
#pragma unroll
      for (int i = 0; i < 4; ++i) {
        const int l = ty * 4 + i;
#pragma unroll
        for (int j = 0; j < 4; ++j) {
          const int e = cb4 + j;
          s_m[l][e] = sigm(acc[i][j] + s_last[e] + nb[e]);
        }
      }
    }
  }
  __syncthreads();   // B8

  // ---- E3: coef[l] = (m[l] . nv) * mask[l] ----
  if (t < LLEN) {
    float acc = 0.0f;
#pragma unroll 4
    for (int e = 0; e < DD; ++e) acc += s_m[t][e] * nv[e];
    s_coef[t] = acc * mask[b * LLEN + t];
  }
  __syncthreads();   // B9

  // ---- E4: ma[d] = sum_l coef[l] * seq_h[l][d] -> mab ----
  if (t < DD) {
    float acc = 0.0f;
#pragma unroll 4
    for (int l = 0; l < LLEN; ++l) acc += s_coef[l] * s_fin[s_idx[l]][t];
    mab[(size_t)b * KP + t] = f2bf(acc);
  } else if (t < KP) {
    mab[(size_t)b * KP + t] = 0;
  }
}

// ---------------------------------------------------------------------------
// K4: logits = mab @ eb2[1:]^T via MFMA — round-5 tiling (parked at ~64 us:
// 102 MB mandatory output at the ~1.6 TB/s streaming-write plateau).
// Round-7 change: per-row exp-sums accumulate via atomicAdd into sumrow[512]
// (zeroed by k_cvt_all) instead of the sump[512][391] matrix.
// ---------------------------------------------------------------------------
__global__ __launch_bounds__(256) void k_logits_mfma(
    const ushort_t* __restrict__ eb2, const ushort_t* __restrict__ mab,
    float* __restrict__ out, float* __restrict__ sumrow)
{
  __shared__ float s_o[16][512];   // block C tile: 16 rows x 512 cols
  const int t = threadIdx.x;
  const int wave = t >> 6, lane = t & 63;
  const int n16 = lane & 15, quad = lane >> 4;
  const int bid = blockIdx.x;
  const int xcd = bid & 7;
  const int j = bid >> 3;                    // 0..415
  const int grpl = j >> 5;                   // local col-group 0..12
  const int lgmax = (xcd < 2) ? 13 : 12;     // 98 = 2*13 + 6*12
  if (grpl >= lgmax) return;
  const int stripe = j & 31;                 // fast-varying: 32 row-stripes
  const int cg = ((xcd < 2) ? xcd * 13 : 26 + (xcd - 2) * 12) + grpl; // 0..97
  const int m0 = stripe * 16;
  const int cblk = cg * 4 + wave;            // this wave's 128-col block

  short8 afr[4];
  const ushort_t* abase = mab + (size_t)(m0 + n16) * KP + quad * 8;
#pragma unroll
  for (int ks = 0; ks < 4; ++ks) afr[ks] = *(const short8*)(abase + ks * 32);

  float s[4] = {0.0f, 0.0f, 0.0f, 0.0f};
  if (cblk < NCB) {
#pragma unroll
    for (int sub = 0; sub < 8; ++sub) {
      const int c = cblk * 128 + sub * 16 + n16;
      const ushort_t* bbase = eb2 + (size_t)((c < NM1) ? (c + 1) : 0) * KP + quad * 8;
      f32x4 acc = {0.0f, 0.0f, 0.0f, 0.0f};
#pragma unroll
      for (int ks = 0; ks < 4; ++ks) {
        short8 bfr = *(const short8*)(bbase + ks * 32);
        acc = __builtin_amdgcn_mfma_f32_16x16x32_bf16(afr[ks], bfr, acc, 0, 0, 0);
      }
#pragma unroll
      for (int r = 0; r < 4; ++r) {
        s_o[quad * 4 + r][wave * 128 + sub * 16 + n16] = acc[r];
        if (c < NM1) s[r] += __expf(acc[r] - SHIFT);
      }
    }
  }
  __syncthreads();

  // store: 8 iters x (2 rows x 2048 B contiguous runs)
  float* lgp = out + 1;
  const int half = t >> 7, tc = t & 127;
#pragma unroll
  for (int it = 0; it < 8; ++it) {
    const int row = it * 2 + half;
    const size_t gr = m0 + row;
    f32x4 v = *(const f32x4*)&s_o[row][tc * 4];
    const int c0 = cg * 512 + tc * 4;
    if (c0 + 3 < NM1) {
      __builtin_nontemporal_store(v, (f32x4*)(lgp + gr * NM1 + c0));
    } else {
#pragma unroll
      for (int e = 0; e < 4; ++e)
        if (c0 + e < NM1)
          __builtin_nontemporal_store(v[e], lgp + gr * NM1 + c0 + e);
    }
  }

  if (cblk < NCB) {
    const int row0 = m0 + quad * 4;
#pragma unroll
    for (int r = 0; r < 4; ++r) {
      float x = s[r];
      x += __shfl_xor(x, 1, 64);
      x += __shfl_xor(x, 2, 64);
      x += __shfl_xor(x, 4, 64);
      x += __shfl_xor(x, 8, 64);
      if (n16 == 0) atomicAdd(&sumrow[row0 + r], x);
    }
  }
}

// ---------------------------------------------------------------------------
// K5: fused LSE + loss, single block of 512 threads (one per row).
// ---------------------------------------------------------------------------
__global__ __launch_bounds__(512) void k_lse_loss(
    const float* __restrict__ sumrow, float* __restrict__ out,
    const int* __restrict__ tar)
{
  const int r = threadIdx.x;
  __shared__ float red[8];
  const float* lg = out + 1;
  const int label = tar[r] - 1;
  float rt = lg[(size_t)r * NM1 + label] - (logf(sumrow[r]) + SHIFT);
  for (int m = 1; m < 64; m <<= 1) rt += __shfl_xor(rt, m, 64);
  if ((r & 63) == 0) red[r >> 6] = rt;
  __syncthreads();
  if (r == 0) {
    float tot = 0.0f;
#pragma unroll
    for (int i = 0; i < 8; ++i) tot += red[i];
    out[0] = -tot / (float)BB;
  }
}

// ---------------------------------------------------------------------------
extern "C" void kernel_launch(void* const* d_in, const int* in_sizes, int n_in,
                              void* d_out, int out_size, void* d_ws, size_t ws_size,
                              hipStream_t stream)
{
  (void)in_sizes; (void)n_in; (void)out_size; (void)ws_size;
  const float* adj_in  = (const float*)d_in[0];
  const float* adj_out = (const float*)d_in[1];
  const int*   item    = (const int*)d_in[2];
  const int*   alias_  = (const int*)d_in[3];
  const float* mask    = (const float*)d_in[4];
  const int*   tar     = (const int*)d_in[5];
  const float* emb     = (const float*)d_in[6];
  const float* W_in    = (const float*)d_in[7];
  const float* b_in    = (const float*)d_in[8];
  const float* W_out   = (const float*)d_in[9];
  const float* b_out   = (const float*)d_in[10];
  const float* gk      = (const float*)d_in[11];
  const float* gb      = (const float*)d_in[12];
  const float* ck      = (const float*)d_in[13];
  const float* cbs     = (const float*)d_in[14];
  const float* w1      = (const float*)d_in[15];
  const float* w2      = (const float*)d_in[16];
  const float* nv      = (const float*)d_in[17];
  const float* nb      = (const float*)d_in[18];
  float* out = (float*)d_out;

  // Workspace layout, ushort units (offsets kept from prior rounds).
  ushort_t* usw = (ushort_t*)d_ws;
  ushort_t* eb2  = usw;                    // 50000*128     = 6,400,000
  ushort_t* WioT = usw + 13740032;         // 208*128       = 26,624
  ushort_t* gkT  = usw + 13766656;         // 208*352       = 73,216
  ushort_t* ckT  = usw + 13839872;         // 112*352       = 39,424
  ushort_t* mab  = usw + 13879296;         // 512*128       = 65,536
  float* fpool   = (float*)(usw + 13944832);
  float* sumrow  = fpool + 3276800;        // 512 floats

  k_cvt_all <<<dim3(1644), 256, 0, stream>>>(emb, W_in, W_out, gk, ck,
                                             eb2, WioT, gkT, ckT, sumrow);
  k_fused   <<<dim3(512), 512, 0, stream>>>(eb2, item, WioT, b_in, b_out,
                                            adj_in, adj_out, gkT, gb, ckT, cbs,
                                            alias_, mask, w1, w2, nv, nb, mab);
  k_logits_mfma<<<dim3(3328), 256, 0, stream>>>(eb2, mab, out, sumrow);
  k_lse_loss<<<dim3(1), 512, 0, stream>>>(sumrow, out, tar);
}

// Round 8
// 294.987 us; speedup vs baseline: 1.1078x; 1.0591x over previous
//
#include <hip/hip_runtime.h>
#include <math.h>

// Problem constants
#define BB    512
#define NNODE 64
#define LLEN  64
#define DD    100
#define NNODES 50000
#define NM1   49999     // n_nodes - 1
#define KP    128       // padded K for emb/h (4 k-steps of 32)
#define KAV   224       // padded K for av section (7 k-steps)
#define KTOT  352       // KAV + KP
#define NCB   391       // ceil(49999/128) logits col-blocks
#define SHIFT 20.0f

typedef __attribute__((ext_vector_type(8))) short short8;
typedef __attribute__((ext_vector_type(4))) short short4_t;
typedef __attribute__((ext_vector_type(4))) float f32x4;
typedef unsigned short ushort_t;

__device__ __forceinline__ float sigm(float x) { return 1.0f / (1.0f + __expf(-x)); }
__device__ __forceinline__ float mytanh(float x) {
  x = fminf(15.0f, fmaxf(-15.0f, x));
  float e = __expf(-2.0f * x);
  return (1.0f - e) / (1.0f + e);
}
__device__ __forceinline__ float f4c(const float4& v, int k) { return ((const float*)&v)[k]; }
__device__ __forceinline__ ushort_t f2bf(float f) {  // RNE float->bf16
  union { float f; unsigned u; } v; v.f = f;
  unsigned r = v.u + 0x7FFF + ((v.u >> 16) & 1);
  return (ushort_t)(r >> 16);
}
__device__ __forceinline__ float bf2f(ushort_t s) {
  union { unsigned u; float f; } v; v.u = ((unsigned)s) << 16;
  return v.f;
}
__device__ __forceinline__ short8 cvt8(const float* __restrict__ p) {
  float4 v0 = *(const float4*)p, v1 = *(const float4*)(p + 4);
  short8 r;
  r[0] = (short)f2bf(v0.x); r[1] = (short)f2bf(v0.y);
  r[2] = (short)f2bf(v0.z); r[3] = (short)f2bf(v0.w);
  r[4] = (short)f2bf(v1.x); r[5] = (short)f2bf(v1.y);
  r[6] = (short)f2bf(v1.z); r[7] = (short)f2bf(v1.w);
  return r;
}

// ---------------------------------------------------------------------------
// C1: weight conversions only (emb->bf16 now done in-register by consumers).
// grid (287, 3); block (286, y=0) zeroes sumrow[512].
// ---------------------------------------------------------------------------
__global__ __launch_bounds__(256) void k_cvt_w(
    const float* __restrict__ Wi, const float* __restrict__ Wo,
    const float* __restrict__ gk, const float* __restrict__ ck,
    ushort_t* __restrict__ WioT, ushort_t* __restrict__ gkT,
    ushort_t* __restrict__ ckT, float* __restrict__ sumrow)
{
  const int t = threadIdx.x;
  const int y = blockIdx.y;
  const int idx = blockIdx.x * 256 + t;
  if (y == 0) {
    if (blockIdx.x == 286) {          // spare block: zero sumrow
      sumrow[t] = 0.0f;
      sumrow[t + 256] = 0.0f;
      return;
    }
    if (idx >= 208 * 128) return;
    int n = idx >> 7, k = idx & 127;
    float v = 0.0f;
    if (k < DD) {
      if (n < 100) v = Wi[k * DD + n];
      else if (n < 200) v = Wo[k * DD + (n - 100)];
    }
    WioT[idx] = f2bf(v);
  } else if (y == 1) {
    if (idx >= 208 * KTOT) return;
    int n = idx / KTOT, k = idx - n * KTOT;
    float v = 0.0f;
    if (n < 200) {
      if (k < KAV) { if (k < 200) v = gk[k * 200 + n]; }
      else { int kk = k - KAV; if (kk < 100) v = gk[(200 + kk) * 200 + n]; }
    }
    gkT[idx] = f2bf(v);
  } else {
    if (idx >= 112 * KTOT) return;
    int n = idx / KTOT, k = idx - n * KTOT;
    float v = 0.0f;
    if (n < 100) {
      if (k < KAV) { if (k < 200) v = ck[k * DD + n]; }
      else { int kk = k - KAV; if (kk < 100) v = ck[(200 + kk) * DD + n]; }
    }
    ckT[idx] = f2bf(v);
  }
}

// ---------------------------------------------------------------------------
// K1: FUSED fio+av+GRU+attn. One block per batch b, 512 threads (8 waves).
// Round-8: h staged straight from emb fp32 (RNE-converted in-register,
// bit-identical to the old eb2 path) — the 33 MB emb->eb2 conversion kernel
// is gone. LDS pool 80.3 KB => 2 blocks/CU, all 512 blocks resident.
//
// LDS pool (80,320 B):
//   R1 [    0..32255]: s_f[2][112][72]us (A,B)
//                      -> s_rh[64][136]us @0 + s_ub[64][104]us @17408 (C,D)
//                      -> s_m[64][104]f @0 (E2,E3)
//   R2 [32256..61951]: s_av[64][232]us (B..afa reg load) -> s_fin[64][104]f
//   R3 [61952..79359]: s_h[64][136]us (A0..D)
//   SM [79360..]     : s_last[104]f, s_coef[64]f, s_idx[64]i, s_lastid
// ---------------------------------------------------------------------------
__global__ __launch_bounds__(512) void k_fused(
    const float* __restrict__ emb, const int* __restrict__ item,
    const ushort_t* __restrict__ WioT,
    const float* __restrict__ bi, const float* __restrict__ bo,
    const float* __restrict__ adj_in, const float* __restrict__ adj_out,
    const ushort_t* __restrict__ gkT, const float* __restrict__ gb,
    const ushort_t* __restrict__ ckT, const float* __restrict__ cbs,
    const int* __restrict__ alias_, const float* __restrict__ mask,
    const float* __restrict__ w1, const float* __restrict__ w2,
    const float* __restrict__ nv, const float* __restrict__ nb,
    ushort_t* __restrict__ mab)
{
  __shared__ __align__(16) char pool[80320];
  ushort_t (*s_f)[112][72] = (ushort_t (*)[112][72])(pool);
  ushort_t (*s_rh)[136]    = (ushort_t (*)[136])(pool);
  ushort_t (*s_ub)[104]    = (ushort_t (*)[104])(pool + 17408);
  float    (*s_m)[104]     = (float (*)[104])(pool);
  ushort_t (*s_av)[232]    = (ushort_t (*)[232])(pool + 32256);
  float    (*s_fin)[104]   = (float (*)[104])(pool + 32256);
  ushort_t (*s_h)[136]     = (ushort_t (*)[136])(pool + 61952);
  float* s_last   = (float*)(pool + 79360);
  float* s_coef   = (float*)(pool + 79776);
  int*   s_idx    = (int*)(pool + 80032);
  int*   s_lastid = (int*)(pool + 80288);

  const int t = threadIdx.x;
  const int w8 = t >> 6, lane = t & 63;
  const int rw = w8 & 3, ch = w8 >> 2;
  const int n16 = lane & 15, quad = lane >> 4;
  const int b = blockIdx.x;

  // ---- A0: stage h rows from emb fp32 -> s_h bf16 (RNE, = old eb2 path) ----
  {
    const int row = t >> 3, seg = t & 7;   // cols seg*16 .. seg*16+15
    const float* hsrc = emb + (size_t)item[b * 64 + row] * DD + seg * 16;
    short8 o0 = {0, 0, 0, 0, 0, 0, 0, 0};
    short8 o1 = {0, 0, 0, 0, 0, 0, 0, 0};
    if (seg < 6) {                 // cols <= 95: full 16
      o0 = cvt8(hsrc);
      o1 = cvt8(hsrc + 8);
    } else if (seg == 6) {         // cols 96..99 valid
      float4 v = *(const float4*)(hsrc);
      o0[0] = (short)f2bf(v.x); o0[1] = (short)f2bf(v.y);
      o0[2] = (short)f2bf(v.z); o0[3] = (short)f2bf(v.w);
    }                              // seg 7: all pad
    *(short8*)&s_h[row][seg * 16]     = o0;
    *(short8*)&s_h[row][seg * 16 + 8] = o1;
  }
  if (t >= 64 && t < 128) {            // zero s_av cols 200..223 (afa ks=6 pad)
    const int r2 = t - 64;
#pragma unroll
    for (int c = 200; c < 224; ++c) s_av[r2][c] = 0;
  }
  for (int idx = t; idx < 2 * 12 * 64; idx += 512) {   // s_f pad rows 100..111
    int which = idx / 768, rem = idx - which * 768;
    s_f[which][100 + rem / 64][rem & 63] = 0;
  }
  __syncthreads();   // B1

  // af = h fragment for stripe rw (also the GRU's afh)
  short8 af[4];
#pragma unroll
  for (int ks = 0; ks < 4; ++ks)
    af[ks] = *(const short8*)&s_h[rw * 16 + n16][quad * 8 + ks * 32];

  // ---- A: fio = h @ [Wi|Wo] + bias -> s_f (transposed [col][node]) ----
  {
    const int node0 = rw * 16 + quad * 4;
    const int s0 = ch ? 7 : 0, s1 = ch ? 13 : 7;
    for (int sub = s0; sub < s1; ++sub) {
      const ushort_t* brow = WioT + (size_t)(sub * 16 + n16) * KP + quad * 8;
      f32x4 acc = {0.0f, 0.0f, 0.0f, 0.0f};
#pragma unroll
      for (int ks = 0; ks < 4; ++ks)
        acc = __builtin_amdgcn_mfma_f32_16x16x32_bf16(af[ks], *(const short8*)(brow + ks * 32), acc, 0, 0, 0);
      const int col = sub * 16 + n16;
      if (col < 200) {
        const float bias = (col < 100) ? bi[col] : bo[col - 100];
        short4_t st;
#pragma unroll
        for (int r = 0; r < 4; ++r) ((ushort_t*)&st)[r] = f2bf(acc[r] + bias);
        const int which = (col < 100) ? 0 : 1;
        const int c = (col < 100) ? col : col - 100;
        *(short4_t*)&s_f[which][c][node0] = st;
      }
    }
  }
  __syncthreads();   // B2

  // ---- B: av. ch=0: adj_in@fi -> cols 0..99; ch=1: adj_out@fo -> 100..199 ----
  {
    const float* aX = (ch ? adj_out : adj_in)
                      + ((size_t)b * 64 + rw * 16 + n16) * 64 + quad * 8;
    short8 afX[2];
    afX[0] = cvt8(aX); afX[1] = cvt8(aX + 32);
    for (int sub = 0; sub < 7; ++sub) {
      const int col = sub * 16 + n16;
      const ushort_t* bX = &s_f[ch][col][quad * 8];
      f32x4 acc = {0.0f, 0.0f, 0.0f, 0.0f};
#pragma unroll
      for (int ks = 0; ks < 2; ++ks)
        acc = __builtin_amdgcn_mfma_f32_16x16x32_bf16(afX[ks], *(const short8*)(bX + ks * 32), acc, 0, 0, 0);
      if (col < 100) {
#pragma unroll
        for (int r = 0; r < 4; ++r)
          s_av[rw * 16 + quad * 4 + r][ch * 100 + col] = f2bf(acc[r]);
      }
    }
  }
  __syncthreads();   // B3

  // Region1 transitions s_f -> s_rh/s_ub: zero pad cols 100..127 (afr pad)
  if (t < 64) {
#pragma unroll
    for (int c = 100; c < 128; ++c) s_rh[t][c] = 0;
  }
  // afa = av fragment for stripe rw
  short8 afa[7];
#pragma unroll
  for (int ks = 0; ks < 7; ++ks)
    afa[ks] = *(const short8*)&s_av[rw * 16 + n16][quad * 8 + ks * 32];

  // ---- C: gates = sigm([av|h] @ gkT + gb); r*h -> s_rh, u -> s_ub (bf16) ----
  {
    const int s0 = ch ? 7 : 0, s1 = ch ? 13 : 7;
    for (int sub = s0; sub < s1; ++sub) {
      const ushort_t* brow = gkT + (size_t)(sub * 16 + n16) * KTOT + quad * 8;
      f32x4 acc = {0.0f, 0.0f, 0.0f, 0.0f};
#pragma unroll
      for (int ks = 0; ks < 7; ++ks)
        acc = __builtin_amdgcn_mfma_f32_16x16x32_bf16(afa[ks], *(const short8*)(brow + ks * 32), acc, 0, 0, 0);
#pragma unroll
      for (int ks = 0; ks < 4; ++ks)
        acc = __builtin_amdgcn_mfma_f32_16x16x32_bf16(af[ks], *(const short8*)(brow + KAV + ks * 32), acc, 0, 0, 0);
      const int col = sub * 16 + n16;
      if (col < 200) {
        const float bias = gb[col];
#pragma unroll
        for (int r = 0; r < 4; ++r) {
          const int row = rw * 16 + quad * 4 + r;
          const float g = sigm(acc[r] + bias);
          if (col < 100) s_rh[row][col] = f2bf(g * bf2f(s_h[row][col]));
          else           s_ub[row][col - 100] = f2bf(g);
        }
      }
    }
  }
  __syncthreads();   // B4

  // afr = (r*h) fragment
  short8 afr[4];
#pragma unroll
  for (int ks = 0; ks < 4; ++ks)
    afr[ks] = *(const short8*)&s_rh[rw * 16 + n16][quad * 8 + ks * 32];

  // ---- D: c = tanh([av|r*h] @ ckT + cb); fin = u*h + (1-u)*c -> s_fin ----
  {
    const int s0 = ch ? 4 : 0, s1 = ch ? 7 : 4;
    for (int sub = s0; sub < s1; ++sub) {
      const ushort_t* brow = ckT + (size_t)(sub * 16 + n16) * KTOT + quad * 8;
      f32x4 acc = {0.0f, 0.0f, 0.0f, 0.0f};
#pragma unroll
      for (int ks = 0; ks < 7; ++ks)
        acc = __builtin_amdgcn_mfma_f32_16x16x32_bf16(afa[ks], *(const short8*)(brow + ks * 32), acc, 0, 0, 0);
#pragma unroll
      for (int ks = 0; ks < 4; ++ks)
        acc = __builtin_amdgcn_mfma_f32_16x16x32_bf16(afr[ks], *(const short8*)(brow + KAV + ks * 32), acc, 0, 0, 0);
      const int col = sub * 16 + n16;
      if (col < 100) {
        const float bias = cbs[col];
#pragma unroll
        for (int r = 0; r < 4; ++r) {
          const int row = rw * 16 + quad * 4 + r;
          const float c_ = mytanh(acc[r] + bias);
          const float u = bf2f(s_ub[row][col]);
          const float hv = bf2f(s_h[row][col]);
          s_fin[row][col] = u * hv + (1.0f - u) * c_;
        }
      }
    }
  }
  __syncthreads();   // B5

  // ---- E0: lastid (wave0 shuffle reduce) + alias index table ----
  if (t < 64) {
    float v = mask[b * LLEN + t];
    v += __shfl_xor(v, 1, 64);  v += __shfl_xor(v, 2, 64);
    v += __shfl_xor(v, 4, 64);  v += __shfl_xor(v, 8, 64);
    v += __shfl_xor(v, 16, 64); v += __shfl_xor(v, 32, 64);
    if (t == 0) {
      int rm = (int)(v + 0.5f);
      *s_lastid = alias_[b * LLEN + rm - 1];
    }
  } else if (t < 128) {
    s_idx[t - 64] = alias_[b * LLEN + (t - 64)];
  }
  __syncthreads();   // B6

  // ---- E1: s_last[e] = fin[lastid] @ w1 ----
  if (t < DD) {
    const float* lh = s_fin[*s_lastid];
    float acc = 0.0f;
#pragma unroll 4
    for (int k = 0; k < DD; ++k) acc += lh[k] * w1[k * DD + t];
    s_last[t] = acc;
  }
  __syncthreads();   // B7

  // ---- E2: s_m = sigm(seq_h @ w2 + last + nb); 16 ty-groups x 4 rows ----
  {
    const int tx = t & 31, ty = t >> 5, cb4 = tx * 4;
    if (cb4 < DD) {
      float acc[4][4] = {};
      const float* frs[4] = { s_fin[s_idx[ty * 4 + 0]], s_fin[s_idx[ty * 4 + 1]],
                              s_fin[s_idx[ty * 4 + 2]], s_fin[s_idx[ty * 4 + 3]] };
      for (int k4 = 0; k4 < 25; ++k4) {
        float4 bv[4];
#pragma unroll
        for (int kk = 0; kk < 4; ++kk)
          bv[kk] = *(const float4*)(w2 + (size_t)(k4 * 4 + kk) * DD + cb4);
#pragma unroll
        for (int i = 0; i < 4; ++i) {
          float4 a = *(const float4*)(frs[i] + k4 * 4);
#pragma unroll
          for (int kk = 0; kk < 4; ++kk) {
            float av_ = f4c(a, kk);
#pragma unroll
            for (int j = 0; j < 4; ++j) acc[i][j] += av_ * f4c(bv[kk], j);
          }
        }
      }
#pragma unroll
      for (int i = 0; i < 4; ++i) {
        const int l = ty * 4 + i;
#pragma unroll
        for (int j = 0; j < 4; ++j) {
          const int e = cb4 + j;
          s_m[l][e] = sigm(acc[i][j] + s_last[e] + nb[e]);
        }
      }
    }
  }
  __syncthreads();   // B8

  // ---- E3: coef[l] = (m[l] . nv) * mask[l] ----
  if (t < LLEN) {
    float acc = 0.0f;
#pragma unroll 4
    for (int e = 0; e < DD; ++e) acc += s_m[t][e] * nv[e];
    s_coef[t] = acc * mask[b * LLEN + t];
  }
  __syncthreads();   // B9

  // ---- E4: ma[d] = sum_l coef[l] * seq_h[l][d] -> mab ----
  if (t < DD) {
    float acc = 0.0f;
#pragma unroll 4
    for (int l = 0; l < LLEN; ++l) acc += s_coef[l] * s_fin[s_idx[l]][t];
    mab[(size_t)b * KP + t] = f2bf(acc);
  } else if (t < KP) {
    mab[(size_t)b * KP + t] = 0;
  }
}

// ---------------------------------------------------------------------------
// K4: logits = mab @ emb[1:]^T via MFMA — B fragments converted fp32->bf16
// in-register (RNE, bit-identical to the old eb2 path). Round-5 store tiling
// (parked at ~64 us: 102 MB mandatory output at ~1.6 TB/s write plateau).
// Per-XCD emb slice = 13 grp x 512 rows x 400 B = 2.7 MB -> L2-resident.
// ---------------------------------------------------------------------------
__global__ __launch_bounds__(256) void k_logits_mfma(
    const float* __restrict__ emb, const ushort_t* __restrict__ mab,
    float* __restrict__ out, float* __restrict__ sumrow)
{
  __shared__ float s_o[16][512];   // block C tile: 16 rows x 512 cols
  const int t = threadIdx.x;
  const int wave = t >> 6, lane = t & 63;
  const int n16 = lane & 15, quad = lane >> 4;
  const int bid = blockIdx.x;
  const int xcd = bid & 7;
  const int j = bid >> 3;                    // 0..415
  const int grpl = j >> 5;                   // local col-group 0..12
  const int lgmax = (xcd < 2) ? 13 : 12;     // 98 = 2*13 + 6*12
  if (grpl >= lgmax) return;
  const int stripe = j & 31;                 // fast-varying: 32 row-stripes
  const int cg = ((xcd < 2) ? xcd * 13 : 26 + (xcd - 2) * 12) + grpl; // 0..97
  const int m0 = stripe * 16;
  const int cblk = cg * 4 + wave;            // this wave's 128-col block

  short8 afr[4];
  const ushort_t* abase = mab + (size_t)(m0 + n16) * KP + quad * 8;
#pragma unroll
  for (int ks = 0; ks < 4; ++ks) afr[ks] = *(const short8*)(abase + ks * 32);

  float s[4] = {0.0f, 0.0f, 0.0f, 0.0f};
  if (cblk < NCB) {
#pragma unroll
    for (int sub = 0; sub < 8; ++sub) {
      const int c = cblk * 128 + sub * 16 + n16;
      const float* browf = emb + (size_t)((c < NM1) ? (c + 1) : 0) * DD;
      // B fragment: K chunks at cols quad*8 + ks*32 (valid < 100)
      short8 b0 = cvt8(browf + quad * 8);            // <= 24+7  = 31..95? full
      short8 b1 = cvt8(browf + quad * 8 + 32);       // <= 63 full
      short8 b2 = cvt8(browf + quad * 8 + 64);       // <= 95 full
      short8 b3 = {0, 0, 0, 0, 0, 0, 0, 0};         // base 96..120
      if (quad == 0) {                               // cols 96..99 valid
        float4 v = *(const float4*)(browf + 96);
        b3[0] = (short)f2bf(v.x); b3[1] = (short)f2bf(v.y);
        b3[2] = (short)f2bf(v.z); b3[3] = (short)f2bf(v.w);
      }
      f32x4 acc = {0.0f, 0.0f, 0.0f, 0.0f};
      acc = __builtin_amdgcn_mfma_f32_16x16x32_bf16(afr[0], b0, acc, 0, 0, 0);
      acc = __builtin_amdgcn_mfma_f32_16x16x32_bf16(afr[1], b1, acc, 0, 0, 0);
      acc = __builtin_amdgcn_mfma_f32_16x16x32_bf16(afr[2], b2, acc, 0, 0, 0);
      acc = __builtin_amdgcn_mfma_f32_16x16x32_bf16(afr[3], b3, acc, 0, 0, 0);
#pragma unroll
      for (int r = 0; r < 4; ++r) {
        s_o[quad * 4 + r][wave * 128 + sub * 16 + n16] = acc[r];
        if (c < NM1) s[r] += __expf(acc[r] - SHIFT);
      }
    }
  }
  __syncthreads();

  // store: 8 iters x (2 rows x 2048 B contiguous runs)
  float* lgp = out + 1;
  const int half = t >> 7, tc = t & 127;
#pragma unroll
  for (int it = 0; it < 8; ++it) {
    const int row = it * 2 + half;
    const size_t gr = m0 + row;
    f32x4 v = *(const f32x4*)&s_o[row][tc * 4];
    const int c0 = cg * 512 + tc * 4;
    if (c0 + 3 < NM1) {
      __builtin_nontemporal_store(v, (f32x4*)(lgp + gr * NM1 + c0));
    } else {
#pragma unroll
      for (int e = 0; e < 4; ++e)
        if (c0 + e < NM1)
          __builtin_nontemporal_store(v[e], lgp + gr * NM1 + c0 + e);
    }
  }

  if (cblk < NCB) {
    const int row0 = m0 + quad * 4;
#pragma unroll
    for (int r = 0; r < 4; ++r) {
      float x = s[r];
      x += __shfl_xor(x, 1, 64);
      x += __shfl_xor(x, 2, 64);
      x += __shfl_xor(x, 4, 64);
      x += __shfl_xor(x, 8, 64);
      if (n16 == 0) atomicAdd(&sumrow[row0 + r], x);
    }
  }
}

// ---------------------------------------------------------------------------
// K5: fused LSE + loss, single block of 512 threads (one per row).
// ---------------------------------------------------------------------------
__global__ __launch_bounds__(512) void k_lse_loss(
    const float* __restrict__ sumrow, float* __restrict__ out,
    const int* __restrict__ tar)
{
  const int r = threadIdx.x;
  __shared__ float red[8];
  const float* lg = out + 1;
  const int label = tar[r] - 1;
  float rt = lg[(size_t)r * NM1 + label] - (logf(sumrow[r]) + SHIFT);
  for (int m = 1; m < 64; m <<= 1) rt += __shfl_xor(rt, m, 64);
  if ((r & 63) == 0) red[r >> 6] = rt;
  __syncthreads();
  if (r == 0) {
    float tot = 0.0f;
#pragma unroll
    for (int i = 0; i < 8; ++i) tot += red[i];
    out[0] = -tot / (float)BB;
  }
}

// ---------------------------------------------------------------------------
extern "C" void kernel_launch(void* const* d_in, const int* in_sizes, int n_in,
                              void* d_out, int out_size, void* d_ws, size_t ws_size,
                              hipStream_t stream)
{
  (void)in_sizes; (void)n_in; (void)out_size; (void)ws_size;
  const float* adj_in  = (const float*)d_in[0];
  const float* adj_out = (const float*)d_in[1];
  const int*   item    = (const int*)d_in[2];
  const int*   alias_  = (const int*)d_in[3];
  const float* mask    = (const float*)d_in[4];
  const int*   tar     = (const int*)d_in[5];
  const float* emb     = (const float*)d_in[6];
  const float* W_in    = (const float*)d_in[7];
  const float* b_in    = (const float*)d_in[8];
  const float* W_out   = (const float*)d_in[9];
  const float* b_out   = (const float*)d_in[10];
  const float* gk      = (const float*)d_in[11];
  const float* gb      = (const float*)d_in[12];
  const float* ck      = (const float*)d_in[13];
  const float* cbs     = (const float*)d_in[14];
  const float* w1      = (const float*)d_in[15];
  const float* w2      = (const float*)d_in[16];
  const float* nv      = (const float*)d_in[17];
  const float* nb      = (const float*)d_in[18];
  float* out = (float*)d_out;

  // Workspace layout, ushort units (eb2 removed; offsets kept stable).
  ushort_t* usw = (ushort_t*)d_ws;
  ushort_t* WioT = usw + 13740032;         // 208*128       = 26,624
  ushort_t* gkT  = usw + 13766656;         // 208*352       = 73,216
  ushort_t* ckT  = usw + 13839872;         // 112*352       = 39,424
  ushort_t* mab  = usw + 13879296;         // 512*128       = 65,536
  float* fpool   = (float*)(usw + 13944832);
  float* sumrow  = fpool + 3276800;        // 512 floats

  k_cvt_w   <<<dim3(287, 3), 256, 0, stream>>>(W_in, W_out, gk, ck,
                                               WioT, gkT, ckT, sumrow);
  k_fused   <<<dim3(512), 512, 0, stream>>>(emb, item, WioT, b_in, b_out,
                                            adj_in, adj_out, gkT, gb, ckT, cbs,
                                            alias_, mask, w1, w2, nv, nb, mab);
  k_logits_mfma<<<dim3(3328), 256, 0, stream>>>(emb, mab, out, sumrow);
  k_lse_loss<<<dim3(1), 512, 0, stream>>>(sumrow, out, tar);
}